// Round 11
// baseline (239.304 us; speedup 1.0000x reference)
//
#include <hip/hip_runtime.h>
#include <hip/hip_bf16.h>
#include <math.h>

// B=8, H=W=32, dim=768, heads=12, hd=64, N=1024, B*heads=96, M=8192
#define DIM   768
#define NHEAD 12
#define NQ    1024

typedef short  short8  __attribute__((ext_vector_type(8)));
typedef unsigned short us8 __attribute__((ext_vector_type(8)));
typedef float  f32x16  __attribute__((ext_vector_type(16)));

#if __has_builtin(__builtin_amdgcn_exp2f)
#define EXP2(x) __builtin_amdgcn_exp2f(x)
#else
#define EXP2(x) __expf(0.69314718056f * (x))
#endif
#define LOG2E 1.44269504089f

__device__ inline ushort f2b(float f) {
  union { float f; unsigned u; } c; c.f = f;
  unsigned r = (c.u + 0x7FFFu + ((c.u >> 16) & 1u)) >> 16;
  return (ushort)r;
}
__device__ inline float b2f(ushort h) {
  union { unsigned u; float f; } c; c.u = ((unsigned)h) << 16;
  return c.f;
}
__device__ inline ushort4 cvt4(float4 v) {
  ushort4 o; o.x = f2b(v.x); o.y = f2b(v.y); o.z = f2b(v.z); o.w = f2b(v.w);
  return o;
}
// pack two f32 -> bf16x2 (round-half-up; 1 v_perm after 2 adds)
__device__ inline unsigned pkr(float a, float b) {
  union { float f; unsigned u; } ca, cb; ca.f = a; cb.f = b;
  return __builtin_amdgcn_perm(cb.u + 0x8000u, ca.u + 0x8000u, 0x07060302u);
}
// async global->LDS, 16 B per lane; LDS dest = wave-uniform base + lane*16
__device__ __forceinline__ void gload16(const void* g, void* l) {
  __builtin_amdgcn_global_load_lds(
      (const __attribute__((address_space(1))) void*)g,
      (__attribute__((address_space(3))) void*)l, 16, 0, 0);
}

// ---------------------------------------------------------------------------
// prep: x -> bf16 Xb;  qkv_w -> Wqt (2304x768 bf16, T);  proj_w -> Wpt (T)
// ---------------------------------------------------------------------------
__global__ __launch_bounds__(256) void prep(
    const float* __restrict__ x, const float* __restrict__ qkv_w,
    const float* __restrict__ proj_w, ushort* __restrict__ Xb,
    ushort* __restrict__ Wqt, ushort* __restrict__ Wpt) {
  __shared__ ushort Ts[64][68];
  const int blk = blockIdx.x, tid = threadIdx.x;
  if (blk < 768) {
    const float4* src = (const float4*)x;
    ushort4* dst = (ushort4*)Xb;
    int base = blk * 2048;
#pragma unroll
    for (int it = 0; it < 8; ++it) {
      int i = base + it * 256 + tid;
      dst[i] = cvt4(src[i]);
    }
    return;
  }
  const float* W; ushort* Wt; int ncols, tk, tn;
  if (blk < 1200) { int t = blk - 768;  W = qkv_w; Wt = Wqt; ncols = 2304; tk = t % 12; tn = t / 12; }
  else            { int t = blk - 1200; W = proj_w; Wt = Wpt; ncols = 768; tk = t % 12; tn = t / 12; }
  const int kb = tk * 64, nb = tn * 64;
#pragma unroll
  for (int rr = 0; rr < 4; ++rr) {
    int r = (tid >> 4) + rr * 16, c4 = (tid & 15) * 4;
    float4 w = *(const float4*)(W + (size_t)(kb + r) * ncols + nb + c4);
    *(ushort4*)&Ts[r][c4] = cvt4(w);
  }
  __syncthreads();
#pragma unroll
  for (int wwi = 0; wwi < 2; ++wwi) {
    int n = (tid >> 3) + wwi * 32, k8 = (tid & 7) * 8;
    us8 v;
#pragma unroll
    for (int j = 0; j < 8; ++j) v[j] = Ts[k8 + j][n];
    *(us8*)(Wt + (size_t)(nb + n) * 768 + kb + k8) = v;
  }
}

// ---------------------------------------------------------------------------
// QKV bf16 MFMA GEMM (128x128, BK=64), gload16 + XOR swizzle, XCD-swizzled.
// V-region cols written transposed to VTg.
// ---------------------------------------------------------------------------
__global__ __launch_bounds__(256, 4) void gemm_qkv(
    const ushort* __restrict__ A, const ushort* __restrict__ BT,
    const float* __restrict__ bias, ushort* __restrict__ Cp,
    ushort* __restrict__ VTg) {
  __shared__ __align__(16) ushort As[128 * 64];
  __shared__ __align__(16) ushort Bs[128 * 64];
  const int tid = threadIdx.x;
  const int flat = blockIdx.x;
  const int g = flat >> 3;
  const int by = (flat & 7) * 8 + g / 18;
  const int bx = g % 18;
  const int bm = by * 128, bn = bx * 128;
  const int lane = tid & 63, wv = tid >> 6;
  const int l31 = lane & 31, lh = lane >> 5;
  const int wm = (wv >> 1) * 64, wn = (wv & 1) * 64;
  const int xr = l31 & 7;

  const int dr = lane >> 3;
  const int ccol = ((lane & 7) ^ dr) * 8;
  const ushort* ag = A + (size_t)(bm + wv * 32 + dr) * 768 + ccol;
  const ushort* bg = BT + (size_t)(bn + wv * 32 + dr) * 768 + ccol;
  ushort* al = &As[wv * 32 * 64];
  ushort* bl = &Bs[wv * 32 * 64];

  f32x16 acc[2][2];
#pragma unroll
  for (int i = 0; i < 2; ++i)
#pragma unroll
    for (int j = 0; j < 2; ++j)
#pragma unroll
      for (int r = 0; r < 16; ++r) acc[i][j][r] = 0.f;

  for (int kt = 0; kt < 768; kt += 64) {
    __syncthreads();
#pragma unroll
    for (int wi = 0; wi < 4; ++wi) {
      gload16(ag + kt + wi * (8 * 768), al + wi * 512);
      gload16(bg + kt + wi * (8 * 768), bl + wi * 512);
    }
    __syncthreads();
#pragma unroll
    for (int ks = 0; ks < 4; ++ks) {
      const int ca = ((ks * 2 + lh) ^ xr) * 8;
      short8 a0 = *(const short8*)&As[(wm + l31) * 64 + ca];
      short8 a1 = *(const short8*)&As[(wm + 32 + l31) * 64 + ca];
      short8 b0 = *(const short8*)&Bs[(wn + l31) * 64 + ca];
      short8 b1 = *(const short8*)&Bs[(wn + 32 + l31) * 64 + ca];
      acc[0][0] = __builtin_amdgcn_mfma_f32_32x32x16_bf16(a0, b0, acc[0][0], 0, 0, 0);
      acc[0][1] = __builtin_amdgcn_mfma_f32_32x32x16_bf16(a0, b1, acc[0][1], 0, 0, 0);
      acc[1][0] = __builtin_amdgcn_mfma_f32_32x32x16_bf16(a1, b0, acc[1][0], 0, 0, 0);
      acc[1][1] = __builtin_amdgcn_mfma_f32_32x32x16_bf16(a1, b1, acc[1][1], 0, 0, 0);
    }
  }

  if (bn < 1536) {
#pragma unroll
    for (int mb = 0; mb < 2; ++mb)
#pragma unroll
      for (int nb = 0; nb < 2; ++nb) {
        int col = bn + wn + nb * 32 + l31;
        float bv = bias[col];
#pragma unroll
        for (int reg = 0; reg < 16; ++reg) {
          int row = bm + wm + mb * 32 + (reg & 3) + 8 * (reg >> 2) + 4 * lh;
          Cp[(size_t)row * 2304 + col] = f2b(acc[mb][nb][reg] + bv);
        }
      }
  } else {
    const int b_ = bm >> 10;
    const int nbase = (bm & 1023) + wm;
#pragma unroll
    for (int nb = 0; nb < 2; ++nb) {
      int col = bn + wn + nb * 32 + l31;          // 1536..2303
      float bv = bias[col];
      int hd_ = col - 1536;
      int h_ = hd_ >> 6, d_ = hd_ & 63;
      ushort* vrow = VTg + ((size_t)(b_ * NHEAD + h_) * 64 + d_) * NQ;
#pragma unroll
      for (int mb = 0; mb < 2; ++mb)
#pragma unroll
        for (int g2 = 0; g2 < 4; ++g2) {
          int n = nbase + mb * 32 + 8 * g2 + 4 * lh;
          ushort4 st;
          st.x = f2b(acc[mb][nb][4 * g2 + 0] + bv);
          st.y = f2b(acc[mb][nb][4 * g2 + 1] + bv);
          st.z = f2b(acc[mb][nb][4 * g2 + 2] + bv);
          st.w = f2b(acc[mb][nb][4 * g2 + 3] + bv);
          *(ushort4*)(vrow + n) = st;
        }
    }
  }
}

// ---------------------------------------------------------------------------
// Proj GEMM: fp32 out = A(8192x768 bf16) @ Wpt^T + bias. 128m x 64n tiles.
// ---------------------------------------------------------------------------
__global__ __launch_bounds__(256, 4) void gemm_proj(
    const ushort* __restrict__ A, const ushort* __restrict__ BT,
    const float* __restrict__ bias, float* __restrict__ C) {
  __shared__ __align__(16) ushort As[128 * 64];
  __shared__ __align__(16) ushort Bs[64 * 64];
  const int tid = threadIdx.x;
  const int flat = blockIdx.x;
  const int g = flat >> 3;
  const int by = (flat & 7) * 8 + g / 12;
  const int bx = g % 12;
  const int bm = by * 128, bn = bx * 64;
  const int lane = tid & 63, wv = tid >> 6;
  const int l31 = lane & 31, lh = lane >> 5;
  const int wm = (wv >> 1) * 64, wn = (wv & 1) * 32;
  const int xr = l31 & 7;

  const int dr = lane >> 3;
  const int ccol = ((lane & 7) ^ dr) * 8;
  const ushort* ag = A + (size_t)(bm + wv * 32 + dr) * 768 + ccol;
  const ushort* bg = BT + (size_t)(bn + wv * 16 + dr) * 768 + ccol;
  ushort* al = &As[wv * 32 * 64];
  ushort* bl = &Bs[wv * 16 * 64];

  f32x16 acc0, acc1;
#pragma unroll
  for (int r = 0; r < 16; ++r) { acc0[r] = 0.f; acc1[r] = 0.f; }

  for (int kt = 0; kt < 768; kt += 64) {
    __syncthreads();
#pragma unroll
    for (int wi = 0; wi < 4; ++wi)
      gload16(ag + kt + wi * (8 * 768), al + wi * 512);
    gload16(bg + kt,            bl);
    gload16(bg + kt + 8 * 768,  bl + 512);
    __syncthreads();
#pragma unroll
    for (int ks = 0; ks < 4; ++ks) {
      const int ca = ((ks * 2 + lh) ^ xr) * 8;
      short8 a0 = *(const short8*)&As[(wm + l31) * 64 + ca];
      short8 a1 = *(const short8*)&As[(wm + 32 + l31) * 64 + ca];
      short8 b0 = *(const short8*)&Bs[(wn + l31) * 64 + ca];
      acc0 = __builtin_amdgcn_mfma_f32_32x32x16_bf16(a0, b0, acc0, 0, 0, 0);
      acc1 = __builtin_amdgcn_mfma_f32_32x32x16_bf16(a1, b0, acc1, 0, 0, 0);
    }
  }

  const int col = bn + wn + l31;
  const float bv = bias[col];
#pragma unroll
  for (int reg = 0; reg < 16; ++reg) {
    int row = bm + wm + (reg & 3) + 8 * (reg >> 2) + 4 * lh;
    C[(size_t)row * 768 + col]        = acc0[reg] + bv;
    C[(size_t)(row + 32) * 768 + col] = acc1[reg] + bv;
  }
}

// ---------------------------------------------------------------------------
// MFMA flash attention, S^T formulation, fused rel-pos bias.  LDS = exactly
// 32 KB -> 5 blocks/CU:
//   R0 (16 KB): Q stage (gload16, XOR-swizzled) -> after aq hoist reused as
//               Pb2 (4 waves x 32x32, stride-32: 2-way aliasing = free) at
//               [0,4096) + rhs[32 hk][128 q] at [4096,8192).
//   R1 (16 KB): rel tables (x log2e, XOR-swizzled) -> U scratch -> Ks|VT.
// Barrier choreography per R9: hoists (reads) / barrier / overlay writes.
// ---------------------------------------------------------------------------
__global__ __launch_bounds__(256, 5) void attn_mfma(
    const ushort* __restrict__ QKV, const ushort* __restrict__ VTg,
    const float* __restrict__ rph, const float* __restrict__ rpw,
    ushort* __restrict__ O) {
  __shared__ __align__(16) ushort L[16384];   // 32 KB
  ushort* const R0 = L;            // Q -> Pb2 + rhs
  ushort* const R1 = L + 8192;     // tables -> U -> Ks | VT

  const int tid = threadIdx.x;
  const int bh = blockIdx.x % 96;
  const int qt = blockIdx.x / 96;
  const int b = bh / NHEAD, h = bh % NHEAD;
  const int n0 = qt * 128;
  const int lane = tid & 63, wv = tid >> 6;
  const int l31 = lane & 31, lh = lane >> 5;
  const int wb = wv * 32;
  const int xr = l31 & 7;

  const ushort* qb = QKV + (size_t)b * NQ * 2304 + h * 64;
  const ushort* kb = qb + DIM;
  const ushort* vtg = VTg + (size_t)bh * 64 * NQ;

  const int dr = lane >> 3;
  const int ccol = ((lane & 7) ^ dr) * 8;

  // ---- stage Q (128x64) via gload16, XOR-swizzled lane-linear ----
  {
    const ushort* qg = qb + (size_t)(n0 + wv * 32 + dr) * 2304 + ccol;
    ushort* ql = R0 + wv * 32 * 64;
#pragma unroll
    for (int wi = 0; wi < 4; ++wi)
      gload16(qg + (size_t)wi * 8 * 2304, ql + wi * 512);
  }
  // ---- stage rel tables x LOG2E into R1 (rph at 0, rpw at 4096), XOR ----
#pragma unroll
  for (int it = 0; it < 4; ++it) {
    int item = tid + 256 * it;          // 0..1023: 64 rows x 16 ushort4
    int r = item >> 4, c4 = (item & 15) * 4;
    int sw = r * 64 + (((c4 >> 3) ^ (r & 7)) << 3) + (c4 & 7);
    if (r < 63) {
      float4 vh = *(const float4*)(rph + r * 64 + c4);
      vh.x *= LOG2E; vh.y *= LOG2E; vh.z *= LOG2E; vh.w *= LOG2E;
      *(ushort4*)&R1[sw] = cvt4(vh);
      float4 vw = *(const float4*)(rpw + r * 64 + c4);
      vw.x *= LOG2E; vw.y *= LOG2E; vw.z *= LOG2E; vw.w *= LOG2E;
      *(ushort4*)&R1[4096 + sw] = cvt4(vw);
    } else {
      ushort4 z = {0, 0, 0, 0};
      *(ushort4*)&R1[sw] = z;
      *(ushort4*)&R1[4096 + sw] = z;
    }
  }
  __syncthreads();   // ① staging done (gload16 drained by barrier semantics)

  // ---- hoist Q fragments + table fragments (ALL LDS reads before ②) ----
  short8 aq[4];
#pragma unroll
  for (int ks = 0; ks < 4; ++ks)
    aq[ks] = *(const short8*)&R0[(wb + l31) * 64 + ((ks * 2 + lh) ^ xr) * 8];

  const int rA = qt * 4 + wv + 31 - l31;       // rph row for this lane
  short8 ah[4];
#pragma unroll
  for (int ks = 0; ks < 4; ++ks)
    ah[ks] = *(const short8*)&R1[rA * 64 + ((ks * 2 + lh) ^ (rA & 7)) * 8];
  short8 aw[8];
#pragma unroll
  for (int ub = 0; ub < 2; ++ub) {
    const int rB = ub * 32 + l31;
#pragma unroll
    for (int ks = 0; ks < 4; ++ks)
      aw[ub * 4 + ks] =
          *(const short8*)&R1[4096 + rB * 64 + ((ks * 2 + lh) ^ (rB & 7)) * 8];
  }
  __syncthreads();   // ② all R0/R1 reads drained before overlay writes

  // ---- rh / rw MFMAs (register-only) ----
  f32x16 sh, su0, su1;
#pragma unroll
  for (int i = 0; i < 16; ++i) { sh[i] = 0.f; su0[i] = 0.f; su1[i] = 0.f; }
#pragma unroll
  for (int ks = 0; ks < 4; ++ks) {
    sh  = __builtin_amdgcn_mfma_f32_32x32x16_bf16(ah[ks],     aq[ks], sh,  0, 0, 0);
    su0 = __builtin_amdgcn_mfma_f32_32x32x16_bf16(aw[ks],     aq[ks], su0, 0, 0, 0);
    su1 = __builtin_amdgcn_mfma_f32_32x32x16_bf16(aw[4 + ks], aq[ks], su1, 0, 0, 0);
  }

  // overlays (wave-column-private; DS is in-order within a wave)
  ushort* Pb2 = R0 + wv * 1024;        // [32 q][32 j]
  ushort* rhs = R0 + 4096;             // [32 hk][128 q]
#pragma unroll
  for (int reg = 0; reg < 16; ++reg) {
    int rm = (reg & 3) + 8 * (reg >> 2) + 4 * lh;
    rhs[rm * 128 + wb + l31] = f2b(sh[reg]);          // rm = hk
    R1[rm * 128 + wb + l31]        = f2b(su0[reg]);   // U rows 0..31
    R1[(32 + rm) * 128 + wb + l31] = f2b(su1[reg]);   // U rows 32..63
  }
  float rwv[16];
#pragma unroll
  for (int reg = 0; reg < 16; ++reg) {
    int rm = (reg & 3) + 8 * (reg >> 2) + 4 * lh;
    rwv[reg] = b2f(R1[(31 + l31 - rm) * 128 + wb + l31]);  // wq=l31, wk=rm
  }

  // K/V staging ptrs
  const ushort* kg = kb + (size_t)(wv * 16 + dr) * 2304 + ccol;
  const ushort* vg = vtg + (size_t)(wv * 16 + dr) * NQ + ccol;
  ushort* kl = R1 + wv * 16 * 64;           // Ks at R1[0,4096)
  ushort* vl = R1 + 4096 + wv * 16 * 64;    // VT at R1[4096,8192)

  f32x16 oacc0, oacc1;
#pragma unroll
  for (int i = 0; i < 16; ++i) { oacc0[i] = 0.f; oacc1[i] = 0.f; }
  float lacc = 0.f;

  for (int t = 0; t < 16; ++t) {
    const int kt = t * 64;
    __syncthreads();   // ③ prev tile / prologue U reads done before restage
    gload16(kg + (size_t)kt * 2304,              kl);
    gload16(kg + (size_t)kt * 2304 + 8 * 2304,   kl + 512);
    gload16(vg + kt,                             vl);
    gload16(vg + kt + 8 * NQ,                    vl + 512);
    __syncthreads();

    const float rh0 = b2f(rhs[(2 * t) * 128 + wb + l31]);
    const float rh1 = b2f(rhs[(2 * t + 1) * 128 + wb + l31]);

#pragma unroll
    for (int cb = 0; cb < 2; ++cb) {
      f32x16 s;
#pragma unroll
      for (int i = 0; i < 16; ++i) s[i] = 0.f;
#pragma unroll
      for (int ks = 0; ks < 4; ++ks) {
        const int ck = ((ks * 2 + lh) ^ xr) * 8;
        short8 ak = *(const short8*)&R1[(cb * 32 + l31) * 64 + ck];
        s = __builtin_amdgcn_mfma_f32_32x32x16_bf16(ak, aq[ks], s, 0, 0, 0);
      }
      const float rhv = cb ? rh1 : rh0;
#pragma unroll
      for (int g = 0; g < 4; ++g) {
        float p0 = EXP2(fmaf(s[4 * g + 0], 0.18033688f, rwv[4 * g + 0] + rhv));
        float p1 = EXP2(fmaf(s[4 * g + 1], 0.18033688f, rwv[4 * g + 1] + rhv));
        float p2 = EXP2(fmaf(s[4 * g + 2], 0.18033688f, rwv[4 * g + 2] + rhv));
        float p3 = EXP2(fmaf(s[4 * g + 3], 0.18033688f, rwv[4 * g + 3] + rhv));
        lacc += (p0 + p1) + (p2 + p3);
        uint2 pk; pk.x = pkr(p0, p1); pk.y = pkr(p2, p3);
        *(uint2*)&Pb2[l31 * 32 + 8 * g + 4 * lh] = pk;
      }
#pragma unroll
      for (int ks = 0; ks < 2; ++ks) {
        const int cv = ((cb * 4 + ks * 2 + lh) ^ xr) * 8;
        short8 ap  = *(const short8*)&Pb2[l31 * 32 + ks * 16 + lh * 8];
        short8 bv0 = *(const short8*)&R1[4096 + l31 * 64 + cv];
        short8 bv1 = *(const short8*)&R1[4096 + (32 + l31) * 64 + cv];
        oacc0 = __builtin_amdgcn_mfma_f32_32x32x16_bf16(ap, bv0, oacc0, 0, 0, 0);
        oacc1 = __builtin_amdgcn_mfma_f32_32x32x16_bf16(ap, bv1, oacc1, 0, 0, 0);
      }
    }
  }

  lacc += __shfl_xor(lacc, 32);
  const float linv = 1.0f / lacc;
  ushort* ob = O + ((size_t)b * NQ + n0 + wb) * DIM + h * 64;
#pragma unroll
  for (int reg = 0; reg < 16; ++reg) {
    int row = (reg & 3) + 8 * (reg >> 2) + 4 * lh;
    float lq = __shfl(linv, row);
    ob[(size_t)row * DIM + l31]      = f2b(oacc0[reg] * lq);
    ob[(size_t)row * DIM + 32 + l31] = f2b(oacc1[reg] * lq);
  }
}

// ---------------------------------------------------------------------------
extern "C" void kernel_launch(void* const* d_in, const int* in_sizes, int n_in,
                              void* d_out, int out_size, void* d_ws, size_t ws_size,
                              hipStream_t stream) {
  const float* x      = (const float*)d_in[0];
  const float* qkv_w  = (const float*)d_in[1];
  const float* qkv_b  = (const float*)d_in[2];
  const float* proj_w = (const float*)d_in[3];
  const float* proj_b = (const float*)d_in[4];
  const float* rel_h  = (const float*)d_in[5];
  const float* rel_w  = (const float*)d_in[6];
  float* out = (float*)d_out;

  ushort* qkvb = (ushort*)d_ws;                       // 8192 x 2304 bf16 (V region unused)
  ushort* obuf = qkvb + (size_t)8192 * 2304;          // 8192 x 768 bf16
  ushort* Xb   = obuf + (size_t)8192 * DIM;           // 8192 x 768 bf16
  ushort* Wqt  = Xb + (size_t)8192 * DIM;             // 2304 x 768 bf16
  ushort* Wpt  = Wqt + (size_t)2304 * DIM;            // 768 x 768 bf16
  ushort* VTg  = Wpt + (size_t)DIM * DIM;             // 96 x 64 x 1024 bf16

  prep<<<dim3(1344), 256, 0, stream>>>(x, qkv_w, proj_w, Xb, Wqt, Wpt);

  gemm_qkv<<<dim3(1152), 256, 0, stream>>>(Xb, Wqt, qkv_b, qkvb, VTg);

  attn_mfma<<<dim3(96 * 8), 256, 0, stream>>>(qkvb, VTg, rel_h, rel_w, obuf);

  gemm_proj<<<dim3(768), 256, 0, stream>>>(obuf, Wpt, proj_b, out);
}

// Round 12
// 203.430 us; speedup vs baseline: 1.1763x; 1.1763x over previous
//
#include <hip/hip_runtime.h>
#include <hip/hip_bf16.h>
#include <math.h>

// B=8, H=W=32, dim=768, heads=12, hd=64, N=1024, B*heads=96, M=8192
#define DIM   768
#define NHEAD 12
#define NQ    1024

typedef short  short8  __attribute__((ext_vector_type(8)));
typedef unsigned short us8 __attribute__((ext_vector_type(8)));
typedef float  f32x16  __attribute__((ext_vector_type(16)));

#if __has_builtin(__builtin_amdgcn_exp2f)
#define EXP2(x) __builtin_amdgcn_exp2f(x)
#else
#define EXP2(x) __expf(0.69314718056f * (x))
#endif
#define LOG2E 1.44269504089f

__device__ inline ushort f2b(float f) {
  union { float f; unsigned u; } c; c.f = f;
  unsigned r = (c.u + 0x7FFFu + ((c.u >> 16) & 1u)) >> 16;
  return (ushort)r;
}
__device__ inline float b2f(ushort h) {
  union { unsigned u; float f; } c; c.u = ((unsigned)h) << 16;
  return c.f;
}
__device__ inline ushort4 cvt4(float4 v) {
  ushort4 o; o.x = f2b(v.x); o.y = f2b(v.y); o.z = f2b(v.z); o.w = f2b(v.w);
  return o;
}
// pack two f32 -> bf16x2 (round-half-up; 1 v_perm after 2 adds)
__device__ inline unsigned pkr(float a, float b) {
  union { float f; unsigned u; } ca, cb; ca.f = a; cb.f = b;
  return __builtin_amdgcn_perm(cb.u + 0x8000u, ca.u + 0x8000u, 0x07060302u);
}
// async global->LDS, 16 B per lane; LDS dest = wave-uniform base + lane*16
__device__ __forceinline__ void gload16(const void* g, void* l) {
  __builtin_amdgcn_global_load_lds(
      (const __attribute__((address_space(1))) void*)g,
      (__attribute__((address_space(3))) void*)l, 16, 0, 0);
}

// ---------------------------------------------------------------------------
// prep: x -> bf16 Xb;  qkv_w -> Wqt (2304x768 bf16, T);  proj_w -> Wpt (T)
// ---------------------------------------------------------------------------
__global__ __launch_bounds__(256) void prep(
    const float* __restrict__ x, const float* __restrict__ qkv_w,
    const float* __restrict__ proj_w, ushort* __restrict__ Xb,
    ushort* __restrict__ Wqt, ushort* __restrict__ Wpt) {
  __shared__ ushort Ts[64][68];
  const int blk = blockIdx.x, tid = threadIdx.x;
  if (blk < 768) {
    const float4* src = (const float4*)x;
    ushort4* dst = (ushort4*)Xb;
    int base = blk * 2048;
#pragma unroll
    for (int it = 0; it < 8; ++it) {
      int i = base + it * 256 + tid;
      dst[i] = cvt4(src[i]);
    }
    return;
  }
  const float* W; ushort* Wt; int ncols, tk, tn;
  if (blk < 1200) { int t = blk - 768;  W = qkv_w; Wt = Wqt; ncols = 2304; tk = t % 12; tn = t / 12; }
  else            { int t = blk - 1200; W = proj_w; Wt = Wpt; ncols = 768; tk = t % 12; tn = t / 12; }
  const int kb = tk * 64, nb = tn * 64;
#pragma unroll
  for (int rr = 0; rr < 4; ++rr) {
    int r = (tid >> 4) + rr * 16, c4 = (tid & 15) * 4;
    float4 w = *(const float4*)(W + (size_t)(kb + r) * ncols + nb + c4);
    *(ushort4*)&Ts[r][c4] = cvt4(w);
  }
  __syncthreads();
#pragma unroll
  for (int wwi = 0; wwi < 2; ++wwi) {
    int n = (tid >> 3) + wwi * 32, k8 = (tid & 7) * 8;
    us8 v;
#pragma unroll
    for (int j = 0; j < 8; ++j) v[j] = Ts[k8 + j][n];
    *(us8*)(Wt + (size_t)(nb + n) * 768 + kb + k8) = v;
  }
}

// ---------------------------------------------------------------------------
// QKV bf16 MFMA GEMM (128x128, BK=64), gload16 + XOR swizzle, XCD-swizzled.
// V-region cols written transposed to VTg.
// ---------------------------------------------------------------------------
__global__ __launch_bounds__(256, 4) void gemm_qkv(
    const ushort* __restrict__ A, const ushort* __restrict__ BT,
    const float* __restrict__ bias, ushort* __restrict__ Cp,
    ushort* __restrict__ VTg) {
  __shared__ __align__(16) ushort As[128 * 64];
  __shared__ __align__(16) ushort Bs[128 * 64];
  const int tid = threadIdx.x;
  const int flat = blockIdx.x;
  const int g = flat >> 3;
  const int by = (flat & 7) * 8 + g / 18;
  const int bx = g % 18;
  const int bm = by * 128, bn = bx * 128;
  const int lane = tid & 63, wv = tid >> 6;
  const int l31 = lane & 31, lh = lane >> 5;
  const int wm = (wv >> 1) * 64, wn = (wv & 1) * 64;
  const int xr = l31 & 7;

  const int dr = lane >> 3;
  const int ccol = ((lane & 7) ^ dr) * 8;
  const ushort* ag = A + (size_t)(bm + wv * 32 + dr) * 768 + ccol;
  const ushort* bg = BT + (size_t)(bn + wv * 32 + dr) * 768 + ccol;
  ushort* al = &As[wv * 32 * 64];
  ushort* bl = &Bs[wv * 32 * 64];

  f32x16 acc[2][2];
#pragma unroll
  for (int i = 0; i < 2; ++i)
#pragma unroll
    for (int j = 0; j < 2; ++j)
#pragma unroll
      for (int r = 0; r < 16; ++r) acc[i][j][r] = 0.f;

  for (int kt = 0; kt < 768; kt += 64) {
    __syncthreads();
#pragma unroll
    for (int wi = 0; wi < 4; ++wi) {
      gload16(ag + kt + wi * (8 * 768), al + wi * 512);
      gload16(bg + kt + wi * (8 * 768), bl + wi * 512);
    }
    __syncthreads();
#pragma unroll
    for (int ks = 0; ks < 4; ++ks) {
      const int ca = ((ks * 2 + lh) ^ xr) * 8;
      short8 a0 = *(const short8*)&As[(wm + l31) * 64 + ca];
      short8 a1 = *(const short8*)&As[(wm + 32 + l31) * 64 + ca];
      short8 b0 = *(const short8*)&Bs[(wn + l31) * 64 + ca];
      short8 b1 = *(const short8*)&Bs[(wn + 32 + l31) * 64 + ca];
      acc[0][0] = __builtin_amdgcn_mfma_f32_32x32x16_bf16(a0, b0, acc[0][0], 0, 0, 0);
      acc[0][1] = __builtin_amdgcn_mfma_f32_32x32x16_bf16(a0, b1, acc[0][1], 0, 0, 0);
      acc[1][0] = __builtin_amdgcn_mfma_f32_32x32x16_bf16(a1, b0, acc[1][0], 0, 0, 0);
      acc[1][1] = __builtin_amdgcn_mfma_f32_32x32x16_bf16(a1, b1, acc[1][1], 0, 0, 0);
    }
  }

  if (bn < 1536) {
#pragma unroll
    for (int mb = 0; mb < 2; ++mb)
#pragma unroll
      for (int nb = 0; nb < 2; ++nb) {
        int col = bn + wn + nb * 32 + l31;
        float bv = bias[col];
#pragma unroll
        for (int reg = 0; reg < 16; ++reg) {
          int row = bm + wm + mb * 32 + (reg & 3) + 8 * (reg >> 2) + 4 * lh;
          Cp[(size_t)row * 2304 + col] = f2b(acc[mb][nb][reg] + bv);
        }
      }
  } else {
    const int b_ = bm >> 10;
    const int nbase = (bm & 1023) + wm;
#pragma unroll
    for (int nb = 0; nb < 2; ++nb) {
      int col = bn + wn + nb * 32 + l31;          // 1536..2303
      float bv = bias[col];
      int hd_ = col - 1536;
      int h_ = hd_ >> 6, d_ = hd_ & 63;
      ushort* vrow = VTg + ((size_t)(b_ * NHEAD + h_) * 64 + d_) * NQ;
#pragma unroll
      for (int mb = 0; mb < 2; ++mb)
#pragma unroll
        for (int g2 = 0; g2 < 4; ++g2) {
          int n = nbase + mb * 32 + 8 * g2 + 4 * lh;
          ushort4 st;
          st.x = f2b(acc[mb][nb][4 * g2 + 0] + bv);
          st.y = f2b(acc[mb][nb][4 * g2 + 1] + bv);
          st.z = f2b(acc[mb][nb][4 * g2 + 2] + bv);
          st.w = f2b(acc[mb][nb][4 * g2 + 3] + bv);
          *(ushort4*)(vrow + n) = st;
        }
    }
  }
}

// ---------------------------------------------------------------------------
// Proj GEMM: fp32 out = A(8192x768 bf16) @ Wpt^T + bias. 128m x 64n tiles.
// ---------------------------------------------------------------------------
__global__ __launch_bounds__(256, 4) void gemm_proj(
    const ushort* __restrict__ A, const ushort* __restrict__ BT,
    const float* __restrict__ bias, float* __restrict__ C) {
  __shared__ __align__(16) ushort As[128 * 64];
  __shared__ __align__(16) ushort Bs[64 * 64];
  const int tid = threadIdx.x;
  const int flat = blockIdx.x;
  const int g = flat >> 3;
  const int by = (flat & 7) * 8 + g / 12;
  const int bx = g % 12;
  const int bm = by * 128, bn = bx * 64;
  const int lane = tid & 63, wv = tid >> 6;
  const int l31 = lane & 31, lh = lane >> 5;
  const int wm = (wv >> 1) * 64, wn = (wv & 1) * 32;
  const int xr = l31 & 7;

  const int dr = lane >> 3;
  const int ccol = ((lane & 7) ^ dr) * 8;
  const ushort* ag = A + (size_t)(bm + wv * 32 + dr) * 768 + ccol;
  const ushort* bg = BT + (size_t)(bn + wv * 16 + dr) * 768 + ccol;
  ushort* al = &As[wv * 32 * 64];
  ushort* bl = &Bs[wv * 16 * 64];

  f32x16 acc0, acc1;
#pragma unroll
  for (int r = 0; r < 16; ++r) { acc0[r] = 0.f; acc1[r] = 0.f; }

  for (int kt = 0; kt < 768; kt += 64) {
    __syncthreads();
#pragma unroll
    for (int wi = 0; wi < 4; ++wi)
      gload16(ag + kt + wi * (8 * 768), al + wi * 512);
    gload16(bg + kt,            bl);
    gload16(bg + kt + 8 * 768,  bl + 512);
    __syncthreads();
#pragma unroll
    for (int ks = 0; ks < 4; ++ks) {
      const int ca = ((ks * 2 + lh) ^ xr) * 8;
      short8 a0 = *(const short8*)&As[(wm + l31) * 64 + ca];
      short8 a1 = *(const short8*)&As[(wm + 32 + l31) * 64 + ca];
      short8 b0 = *(const short8*)&Bs[(wn + l31) * 64 + ca];
      acc0 = __builtin_amdgcn_mfma_f32_32x32x16_bf16(a0, b0, acc0, 0, 0, 0);
      acc1 = __builtin_amdgcn_mfma_f32_32x32x16_bf16(a1, b0, acc1, 0, 0, 0);
    }
  }

  const int col = bn + wn + l31;
  const float bv = bias[col];
#pragma unroll
  for (int reg = 0; reg < 16; ++reg) {
    int row = bm + wm + (reg & 3) + 8 * (reg >> 2) + 4 * lh;
    C[(size_t)row * 768 + col]        = acc0[reg] + bv;
    C[(size_t)(row + 32) * 768 + col] = acc1[reg] + bv;
  }
}

// ---------------------------------------------------------------------------
// MFMA flash attention, S^T formulation, fused rel-pos bias.  LDS 32 KB.
// R12 fixes vs R11: (a) __launch_bounds__(256,4) + two-phase prologue ->
// no scratch spills (R11: VGPR squeezed to 48, WRITE_SIZE 82MB);
// (b) Pb2 chunk-XOR swizzle at stride 32 (R11's plain stride-32 rows gave a
// 16-way write conflict: bank = (q*16)%32 in {0,16}).
//   R0 (16 KB): Q (gload16, XOR) -> Pb2 [4 waves x 2 KB] + rhs[32][128].
//   R1 (16 KB): rel tables (x log2e, XOR) -> U scratch -> Ks | VT.
// ---------------------------------------------------------------------------
__global__ __launch_bounds__(256, 4) void attn_mfma(
    const ushort* __restrict__ QKV, const ushort* __restrict__ VTg,
    const float* __restrict__ rph, const float* __restrict__ rpw,
    ushort* __restrict__ O) {
  __shared__ __align__(16) ushort L[16384];   // 32 KB
  ushort* const R0 = L;            // Q -> Pb2 + rhs
  ushort* const R1 = L + 8192;     // tables -> U -> Ks | VT

  const int tid = threadIdx.x;
  const int bh = blockIdx.x % 96;
  const int qt = blockIdx.x / 96;
  const int b = bh / NHEAD, h = bh % NHEAD;
  const int n0 = qt * 128;
  const int lane = tid & 63, wv = tid >> 6;
  const int l31 = lane & 31, lh = lane >> 5;
  const int wb = wv * 32;
  const int xr = l31 & 7;
  const int px = l31 & 3;          // Pb2 chunk-XOR key

  const ushort* qb = QKV + (size_t)b * NQ * 2304 + h * 64;
  const ushort* kb = qb + DIM;
  const ushort* vtg = VTg + (size_t)bh * 64 * NQ;

  const int dr = lane >> 3;
  const int ccol = ((lane & 7) ^ dr) * 8;

  // ---- stage Q (128x64) via gload16, XOR-swizzled lane-linear ----
  {
    const ushort* qg = qb + (size_t)(n0 + wv * 32 + dr) * 2304 + ccol;
    ushort* ql = R0 + wv * 32 * 64;
#pragma unroll
    for (int wi = 0; wi < 4; ++wi)
      gload16(qg + (size_t)wi * 8 * 2304, ql + wi * 512);
  }
  // ---- stage rel tables x LOG2E into R1 (rph at 0, rpw at 4096), XOR ----
#pragma unroll
  for (int it = 0; it < 4; ++it) {
    int item = tid + 256 * it;          // 0..1023: 64 rows x 16 ushort4
    int r = item >> 4, c4 = (item & 15) * 4;
    int sw = r * 64 + (((c4 >> 3) ^ (r & 7)) << 3) + (c4 & 7);
    if (r < 63) {
      float4 vh = *(const float4*)(rph + r * 64 + c4);
      vh.x *= LOG2E; vh.y *= LOG2E; vh.z *= LOG2E; vh.w *= LOG2E;
      *(ushort4*)&R1[sw] = cvt4(vh);
      float4 vw = *(const float4*)(rpw + r * 64 + c4);
      vw.x *= LOG2E; vw.y *= LOG2E; vw.z *= LOG2E; vw.w *= LOG2E;
      *(ushort4*)&R1[4096 + sw] = cvt4(vw);
    } else {
      ushort4 z = {0, 0, 0, 0};
      *(ushort4*)&R1[sw] = z;
      *(ushort4*)&R1[4096 + sw] = z;
    }
  }
  __syncthreads();   // ① staging done

  // ---- phase 1: hoist aq + ah only (low liveness) ----
  short8 aq[4];
#pragma unroll
  for (int ks = 0; ks < 4; ++ks)
    aq[ks] = *(const short8*)&R0[(wb + l31) * 64 + ((ks * 2 + lh) ^ xr) * 8];

  const int rA = qt * 4 + wv + 31 - l31;       // rph row for this lane
  short8 ah[4];
#pragma unroll
  for (int ks = 0; ks < 4; ++ks)
    ah[ks] = *(const short8*)&R1[rA * 64 + ((ks * 2 + lh) ^ (rA & 7)) * 8];
  __syncthreads();   // ② all R0-Q reads + rph reads drained

  ushort* Pb2 = R0 + wv * 1024;        // [32 q][4 chunk-XOR x 8]
  ushort* rhs = R0 + 4096;             // [32 hk][128 q]

  // ---- rh: 4 MFMAs, write rhs (R0, column-private) ----
  {
    f32x16 sh;
#pragma unroll
    for (int i = 0; i < 16; ++i) sh[i] = 0.f;
#pragma unroll
    for (int ks = 0; ks < 4; ++ks)
      sh = __builtin_amdgcn_mfma_f32_32x32x16_bf16(ah[ks], aq[ks], sh, 0, 0, 0);
#pragma unroll
    for (int reg = 0; reg < 16; ++reg) {
      int rm = (reg & 3) + 8 * (reg >> 2) + 4 * lh;
      rhs[rm * 128 + wb + l31] = f2b(sh[reg]);
    }
  }

  // ---- phase 2: hoist aw (rpw intact — only R0 written since ②) ----
  short8 aw[8];
#pragma unroll
  for (int ub = 0; ub < 2; ++ub) {
    const int rB = ub * 32 + l31;
#pragma unroll
    for (int ks = 0; ks < 4; ++ks)
      aw[ub * 4 + ks] =
          *(const short8*)&R1[4096 + rB * 64 + ((ks * 2 + lh) ^ (rB & 7)) * 8];
  }
  __syncthreads();   // ②' all rpw reads drained before U overwrites R1

  float rwv[16];
  {
    f32x16 su0;
#pragma unroll
    for (int i = 0; i < 16; ++i) su0[i] = 0.f;
#pragma unroll
    for (int ks = 0; ks < 4; ++ks)
      su0 = __builtin_amdgcn_mfma_f32_32x32x16_bf16(aw[ks], aq[ks], su0, 0, 0, 0);
#pragma unroll
    for (int reg = 0; reg < 16; ++reg) {
      int rm = (reg & 3) + 8 * (reg >> 2) + 4 * lh;
      R1[rm * 128 + wb + l31] = f2b(su0[reg]);        // U rows 0..31
    }
    f32x16 su1;
#pragma unroll
    for (int i = 0; i < 16; ++i) su1[i] = 0.f;
#pragma unroll
    for (int ks = 0; ks < 4; ++ks)
      su1 = __builtin_amdgcn_mfma_f32_32x32x16_bf16(aw[4 + ks], aq[ks], su1, 0, 0, 0);
#pragma unroll
    for (int reg = 0; reg < 16; ++reg) {
      int rm = (reg & 3) + 8 * (reg >> 2) + 4 * lh;
      R1[(32 + rm) * 128 + wb + l31] = f2b(su1[reg]); // U rows 32..63
    }
    // gather (same columns this wave just wrote; DS in-order within wave)
#pragma unroll
    for (int reg = 0; reg < 16; ++reg) {
      int rm = (reg & 3) + 8 * (reg >> 2) + 4 * lh;
      rwv[reg] = b2f(R1[(31 + l31 - rm) * 128 + wb + l31]);  // wq=l31, wk=rm
    }
  }

  // K/V staging ptrs
  const ushort* kg = kb + (size_t)(wv * 16 + dr) * 2304 + ccol;
  const ushort* vg = vtg + (size_t)(wv * 16 + dr) * NQ + ccol;
  ushort* kl = R1 + wv * 16 * 64;           // Ks at R1[0,4096)
  ushort* vl = R1 + 4096 + wv * 16 * 64;    // VT at R1[4096,8192)

  f32x16 oacc0, oacc1;
#pragma unroll
  for (int i = 0; i < 16; ++i) { oacc0[i] = 0.f; oacc1[i] = 0.f; }
  float lacc = 0.f;

  for (int t = 0; t < 16; ++t) {
    const int kt = t * 64;
    __syncthreads();   // ③ prev tile / prologue U reads done before restage
    gload16(kg + (size_t)kt * 2304,              kl);
    gload16(kg + (size_t)kt * 2304 + 8 * 2304,   kl + 512);
    gload16(vg + kt,                             vl);
    gload16(vg + kt + 8 * NQ,                    vl + 512);
    __syncthreads();

    const float rh0 = b2f(rhs[(2 * t) * 128 + wb + l31]);
    const float rh1 = b2f(rhs[(2 * t + 1) * 128 + wb + l31]);

#pragma unroll
    for (int cb = 0; cb < 2; ++cb) {
      f32x16 s;
#pragma unroll
      for (int i = 0; i < 16; ++i) s[i] = 0.f;
#pragma unroll
      for (int ks = 0; ks < 4; ++ks) {
        const int ck = ((ks * 2 + lh) ^ xr) * 8;
        short8 ak = *(const short8*)&R1[(cb * 32 + l31) * 64 + ck];
        s = __builtin_amdgcn_mfma_f32_32x32x16_bf16(ak, aq[ks], s, 0, 0, 0);
      }
      const float rhv = cb ? rh1 : rh0;
#pragma unroll
      for (int g = 0; g < 4; ++g) {
        float p0 = EXP2(fmaf(s[4 * g + 0], 0.18033688f, rwv[4 * g + 0] + rhv));
        float p1 = EXP2(fmaf(s[4 * g + 1], 0.18033688f, rwv[4 * g + 1] + rhv));
        float p2 = EXP2(fmaf(s[4 * g + 2], 0.18033688f, rwv[4 * g + 2] + rhv));
        float p3 = EXP2(fmaf(s[4 * g + 3], 0.18033688f, rwv[4 * g + 3] + rhv));
        lacc += (p0 + p1) + (p2 + p3);
        uint2 pk; pk.x = pkr(p0, p1); pk.y = pkr(p2, p3);
        // chunk-XOR swizzled: j-chunk g lands at (g ^ px)
        *(uint2*)&Pb2[l31 * 32 + ((g ^ px) * 8) + 4 * lh] = pk;
      }
#pragma unroll
      for (int ks = 0; ks < 2; ++ks) {
        const int cv = ((cb * 4 + ks * 2 + lh) ^ xr) * 8;
        short8 ap  = *(const short8*)&Pb2[l31 * 32 + ((ks * 2 + lh) ^ px) * 8];
        short8 bv0 = *(const short8*)&R1[4096 + l31 * 64 + cv];
        short8 bv1 = *(const short8*)&R1[4096 + (32 + l31) * 64 + cv];
        oacc0 = __builtin_amdgcn_mfma_f32_32x32x16_bf16(ap, bv0, oacc0, 0, 0, 0);
        oacc1 = __builtin_amdgcn_mfma_f32_32x32x16_bf16(ap, bv1, oacc1, 0, 0, 0);
      }
    }
  }

  lacc += __shfl_xor(lacc, 32);
  const float linv = 1.0f / lacc;
  ushort* ob = O + ((size_t)b * NQ + n0 + wb) * DIM + h * 64;
#pragma unroll
  for (int reg = 0; reg < 16; ++reg) {
    int row = (reg & 3) + 8 * (reg >> 2) + 4 * lh;
    float lq = __shfl(linv, row);
    ob[(size_t)row * DIM + l31]      = f2b(oacc0[reg] * lq);
    ob[(size_t)row * DIM + 32 + l31] = f2b(oacc1[reg] * lq);
  }
}

// ---------------------------------------------------------------------------
extern "C" void kernel_launch(void* const* d_in, const int* in_sizes, int n_in,
                              void* d_out, int out_size, void* d_ws, size_t ws_size,
                              hipStream_t stream) {
  const float* x      = (const float*)d_in[0];
  const float* qkv_w  = (const float*)d_in[1];
  const float* qkv_b  = (const float*)d_in[2];
  const float* proj_w = (const float*)d_in[3];
  const float* proj_b = (const float*)d_in[4];
  const float* rel_h  = (const float*)d_in[5];
  const float* rel_w  = (const float*)d_in[6];
  float* out = (float*)d_out;

  ushort* qkvb = (ushort*)d_ws;                       // 8192 x 2304 bf16 (V region unused)
  ushort* obuf = qkvb + (size_t)8192 * 2304;          // 8192 x 768 bf16
  ushort* Xb   = obuf + (size_t)8192 * DIM;           // 8192 x 768 bf16
  ushort* Wqt  = Xb + (size_t)8192 * DIM;             // 2304 x 768 bf16
  ushort* Wpt  = Wqt + (size_t)2304 * DIM;            // 768 x 768 bf16
  ushort* VTg  = Wpt + (size_t)DIM * DIM;             // 96 x 64 x 1024 bf16

  prep<<<dim3(1344), 256, 0, stream>>>(x, qkv_w, proj_w, Xb, Wqt, Wpt);

  gemm_qkv<<<dim3(1152), 256, 0, stream>>>(Xb, Wqt, qkv_b, qkvb, VTg);

  attn_mfma<<<dim3(96 * 8), 256, 0, stream>>>(qkvb, VTg, rel_h, rel_w, obuf);

  gemm_proj<<<dim3(768), 256, 0, stream>>>(obuf, Wpt, proj_b, out);
}

// Round 13
// 193.822 us; speedup vs baseline: 1.2347x; 1.0496x over previous
//
#include <hip/hip_runtime.h>
#include <hip/hip_bf16.h>
#include <math.h>

// B=8, H=W=32, dim=768, heads=12, hd=64, N=1024, B*heads=96, M=8192
#define DIM   768
#define NHEAD 12
#define NQ    1024

typedef short  short8  __attribute__((ext_vector_type(8)));
typedef unsigned short us8 __attribute__((ext_vector_type(8)));
typedef float  f32x16  __attribute__((ext_vector_type(16)));

#if __has_builtin(__builtin_amdgcn_exp2f)
#define EXP2(x) __builtin_amdgcn_exp2f(x)
#else
#define EXP2(x) __expf(0.69314718056f * (x))
#endif
#define LOG2E 1.44269504089f

__device__ inline ushort f2b(float f) {
  union { float f; unsigned u; } c; c.f = f;
  unsigned r = (c.u + 0x7FFFu + ((c.u >> 16) & 1u)) >> 16;
  return (ushort)r;
}
__device__ inline float b2f(ushort h) {
  union { unsigned u; float f; } c; c.u = ((unsigned)h) << 16;
  return c.f;
}
__device__ inline ushort4 cvt4(float4 v) {
  ushort4 o; o.x = f2b(v.x); o.y = f2b(v.y); o.z = f2b(v.z); o.w = f2b(v.w);
  return o;
}
// pack two f32 -> bf16x2 (round-half-up; 1 v_perm after 2 adds)
__device__ inline unsigned pkr(float a, float b) {
  union { float f; unsigned u; } ca, cb; ca.f = a; cb.f = b;
  return __builtin_amdgcn_perm(cb.u + 0x8000u, ca.u + 0x8000u, 0x07060302u);
}
// async global->LDS, 16 B per lane; LDS dest = wave-uniform base + lane*16
__device__ __forceinline__ void gload16(const void* g, void* l) {
  __builtin_amdgcn_global_load_lds(
      (const __attribute__((address_space(1))) void*)g,
      (__attribute__((address_space(3))) void*)l, 16, 0, 0);
}

// ---------------------------------------------------------------------------
// prep: x -> bf16 Xb;  qkv_w -> Wqt (2304x768 bf16, T);  proj_w -> Wpt (T)
// ---------------------------------------------------------------------------
__global__ __launch_bounds__(256) void prep(
    const float* __restrict__ x, const float* __restrict__ qkv_w,
    const float* __restrict__ proj_w, ushort* __restrict__ Xb,
    ushort* __restrict__ Wqt, ushort* __restrict__ Wpt) {
  __shared__ ushort Ts[64][68];
  const int blk = blockIdx.x, tid = threadIdx.x;
  if (blk < 768) {
    const float4* src = (const float4*)x;
    ushort4* dst = (ushort4*)Xb;
    int base = blk * 2048;
#pragma unroll
    for (int it = 0; it < 8; ++it) {
      int i = base + it * 256 + tid;
      dst[i] = cvt4(src[i]);
    }
    return;
  }
  const float* W; ushort* Wt; int ncols, tk, tn;
  if (blk < 1200) { int t = blk - 768;  W = qkv_w; Wt = Wqt; ncols = 2304; tk = t % 12; tn = t / 12; }
  else            { int t = blk - 1200; W = proj_w; Wt = Wpt; ncols = 768; tk = t % 12; tn = t / 12; }
  const int kb = tk * 64, nb = tn * 64;
#pragma unroll
  for (int rr = 0; rr < 4; ++rr) {
    int r = (tid >> 4) + rr * 16, c4 = (tid & 15) * 4;
    float4 w = *(const float4*)(W + (size_t)(kb + r) * ncols + nb + c4);
    *(ushort4*)&Ts[r][c4] = cvt4(w);
  }
  __syncthreads();
#pragma unroll
  for (int wwi = 0; wwi < 2; ++wwi) {
    int n = (tid >> 3) + wwi * 32, k8 = (tid & 7) * 8;
    us8 v;
#pragma unroll
    for (int j = 0; j < 8; ++j) v[j] = Ts[k8 + j][n];
    *(us8*)(Wt + (size_t)(nb + n) * 768 + kb + k8) = v;
  }
}

// ---------------------------------------------------------------------------
// QKV bf16 MFMA GEMM (128x128, BK=64), gload16 + XOR swizzle, XCD-swizzled.
// V-region cols written transposed to VTg.
// ---------------------------------------------------------------------------
__global__ __launch_bounds__(256, 4) void gemm_qkv(
    const ushort* __restrict__ A, const ushort* __restrict__ BT,
    const float* __restrict__ bias, ushort* __restrict__ Cp,
    ushort* __restrict__ VTg) {
  __shared__ __align__(16) ushort As[128 * 64];
  __shared__ __align__(16) ushort Bs[128 * 64];
  const int tid = threadIdx.x;
  const int flat = blockIdx.x;
  const int g = flat >> 3;
  const int by = (flat & 7) * 8 + g / 18;
  const int bx = g % 18;
  const int bm = by * 128, bn = bx * 128;
  const int lane = tid & 63, wv = tid >> 6;
  const int l31 = lane & 31, lh = lane >> 5;
  const int wm = (wv >> 1) * 64, wn = (wv & 1) * 64;
  const int xr = l31 & 7;

  const int dr = lane >> 3;
  const int ccol = ((lane & 7) ^ dr) * 8;
  const ushort* ag = A + (size_t)(bm + wv * 32 + dr) * 768 + ccol;
  const ushort* bg = BT + (size_t)(bn + wv * 32 + dr) * 768 + ccol;
  ushort* al = &As[wv * 32 * 64];
  ushort* bl = &Bs[wv * 32 * 64];

  f32x16 acc[2][2];
#pragma unroll
  for (int i = 0; i < 2; ++i)
#pragma unroll
    for (int j = 0; j < 2; ++j)
#pragma unroll
      for (int r = 0; r < 16; ++r) acc[i][j][r] = 0.f;

  for (int kt = 0; kt < 768; kt += 64) {
    __syncthreads();
#pragma unroll
    for (int wi = 0; wi < 4; ++wi) {
      gload16(ag + kt + wi * (8 * 768), al + wi * 512);
      gload16(bg + kt + wi * (8 * 768), bl + wi * 512);
    }
    __syncthreads();
#pragma unroll
    for (int ks = 0; ks < 4; ++ks) {
      const int ca = ((ks * 2 + lh) ^ xr) * 8;
      short8 a0 = *(const short8*)&As[(wm + l31) * 64 + ca];
      short8 a1 = *(const short8*)&As[(wm + 32 + l31) * 64 + ca];
      short8 b0 = *(const short8*)&Bs[(wn + l31) * 64 + ca];
      short8 b1 = *(const short8*)&Bs[(wn + 32 + l31) * 64 + ca];
      acc[0][0] = __builtin_amdgcn_mfma_f32_32x32x16_bf16(a0, b0, acc[0][0], 0, 0, 0);
      acc[0][1] = __builtin_amdgcn_mfma_f32_32x32x16_bf16(a0, b1, acc[0][1], 0, 0, 0);
      acc[1][0] = __builtin_amdgcn_mfma_f32_32x32x16_bf16(a1, b0, acc[1][0], 0, 0, 0);
      acc[1][1] = __builtin_amdgcn_mfma_f32_32x32x16_bf16(a1, b1, acc[1][1], 0, 0, 0);
    }
  }

  if (bn < 1536) {
#pragma unroll
    for (int mb = 0; mb < 2; ++mb)
#pragma unroll
      for (int nb = 0; nb < 2; ++nb) {
        int col = bn + wn + nb * 32 + l31;
        float bv = bias[col];
#pragma unroll
        for (int reg = 0; reg < 16; ++reg) {
          int row = bm + wm + mb * 32 + (reg & 3) + 8 * (reg >> 2) + 4 * lh;
          Cp[(size_t)row * 2304 + col] = f2b(acc[mb][nb][reg] + bv);
        }
      }
  } else {
    const int b_ = bm >> 10;
    const int nbase = (bm & 1023) + wm;
#pragma unroll
    for (int nb = 0; nb < 2; ++nb) {
      int col = bn + wn + nb * 32 + l31;          // 1536..2303
      float bv = bias[col];
      int hd_ = col - 1536;
      int h_ = hd_ >> 6, d_ = hd_ & 63;
      ushort* vrow = VTg + ((size_t)(b_ * NHEAD + h_) * 64 + d_) * NQ;
#pragma unroll
      for (int mb = 0; mb < 2; ++mb)
#pragma unroll
        for (int g2 = 0; g2 < 4; ++g2) {
          int n = nbase + mb * 32 + 8 * g2 + 4 * lh;
          ushort4 st;
          st.x = f2b(acc[mb][nb][4 * g2 + 0] + bv);
          st.y = f2b(acc[mb][nb][4 * g2 + 1] + bv);
          st.z = f2b(acc[mb][nb][4 * g2 + 2] + bv);
          st.w = f2b(acc[mb][nb][4 * g2 + 3] + bv);
          *(ushort4*)(vrow + n) = st;
        }
    }
  }
}

// ---------------------------------------------------------------------------
// Proj GEMM: fp32 out = A(8192x768 bf16) @ Wpt^T + bias. 128m x 64n tiles.
// ---------------------------------------------------------------------------
__global__ __launch_bounds__(256, 4) void gemm_proj(
    const ushort* __restrict__ A, const ushort* __restrict__ BT,
    const float* __restrict__ bias, float* __restrict__ C) {
  __shared__ __align__(16) ushort As[128 * 64];
  __shared__ __align__(16) ushort Bs[64 * 64];
  const int tid = threadIdx.x;
  const int flat = blockIdx.x;
  const int g = flat >> 3;
  const int by = (flat & 7) * 8 + g / 12;
  const int bx = g % 12;
  const int bm = by * 128, bn = bx * 64;
  const int lane = tid & 63, wv = tid >> 6;
  const int l31 = lane & 31, lh = lane >> 5;
  const int wm = (wv >> 1) * 64, wn = (wv & 1) * 32;
  const int xr = l31 & 7;

  const int dr = lane >> 3;
  const int ccol = ((lane & 7) ^ dr) * 8;
  const ushort* ag = A + (size_t)(bm + wv * 32 + dr) * 768 + ccol;
  const ushort* bg = BT + (size_t)(bn + wv * 16 + dr) * 768 + ccol;
  ushort* al = &As[wv * 32 * 64];
  ushort* bl = &Bs[wv * 16 * 64];

  f32x16 acc0, acc1;
#pragma unroll
  for (int r = 0; r < 16; ++r) { acc0[r] = 0.f; acc1[r] = 0.f; }

  for (int kt = 0; kt < 768; kt += 64) {
    __syncthreads();
#pragma unroll
    for (int wi = 0; wi < 4; ++wi)
      gload16(ag + kt + wi * (8 * 768), al + wi * 512);
    gload16(bg + kt,            bl);
    gload16(bg + kt + 8 * 768,  bl + 512);
    __syncthreads();
#pragma unroll
    for (int ks = 0; ks < 4; ++ks) {
      const int ca = ((ks * 2 + lh) ^ xr) * 8;
      short8 a0 = *(const short8*)&As[(wm + l31) * 64 + ca];
      short8 a1 = *(const short8*)&As[(wm + 32 + l31) * 64 + ca];
      short8 b0 = *(const short8*)&Bs[(wn + l31) * 64 + ca];
      acc0 = __builtin_amdgcn_mfma_f32_32x32x16_bf16(a0, b0, acc0, 0, 0, 0);
      acc1 = __builtin_amdgcn_mfma_f32_32x32x16_bf16(a1, b0, acc1, 0, 0, 0);
    }
  }

  const int col = bn + wn + l31;
  const float bv = bias[col];
#pragma unroll
  for (int reg = 0; reg < 16; ++reg) {
    int row = bm + wm + (reg & 3) + 8 * (reg >> 2) + 4 * lh;
    C[(size_t)row * 768 + col]        = acc0[reg] + bv;
    C[(size_t)(row + 32) * 768 + col] = acc1[reg] + bv;
  }
}

// ---------------------------------------------------------------------------
// MFMA flash attention, S^T formulation, fused rel-pos bias, DOUBLE-BUFFERED
// K/V: stage(t+1) -> compute(t) -> barrier. One barrier/tile (was 2), load
// latency hidden behind compute. Grid 768 = 3 blocks/CU is the residency
// bound, so the extra 16 KB buffer is free (51.2 KB still -> 3/CU).
//   R0 (18.4 KB): Q staged by gload16 into first 16 KB (XOR) -> after hoist:
//                 Pb2 (4 x 32x40, R10-proven) + rhs[32][128] at 5120.
//   B0 (16 KB): rph table -> U scratch -> K|V buffer 0.
//   B1 (16 KB): rpw table -> K|V buffer 1.
// ---------------------------------------------------------------------------
__global__ __launch_bounds__(256, 3) void attn_mfma(
    const ushort* __restrict__ QKV, const ushort* __restrict__ VTg,
    const float* __restrict__ rph, const float* __restrict__ rpw,
    ushort* __restrict__ O) {
  __shared__ __align__(16) ushort R0[9216];
  __shared__ __align__(16) ushort B0[8192];
  __shared__ __align__(16) ushort B1[8192];

  const int tid = threadIdx.x;
  const int bh = blockIdx.x % 96;
  const int qt = blockIdx.x / 96;
  const int b = bh / NHEAD, h = bh % NHEAD;
  const int n0 = qt * 128;
  const int lane = tid & 63, wv = tid >> 6;
  const int l31 = lane & 31, lh = lane >> 5;
  const int wb = wv * 32;
  const int xr = l31 & 7;

  const ushort* qb = QKV + (size_t)b * NQ * 2304 + h * 64;
  const ushort* kb = qb + DIM;
  const ushort* vtg = VTg + (size_t)bh * 64 * NQ;

  const int dr = lane >> 3;
  const int ccol = ((lane & 7) ^ dr) * 8;

  // ---- stage Q (128x64) via gload16, XOR-swizzled lane-linear ----
  {
    const ushort* qg = qb + (size_t)(n0 + wv * 32 + dr) * 2304 + ccol;
    ushort* ql = R0 + wv * 32 * 64;
#pragma unroll
    for (int wi = 0; wi < 4; ++wi)
      gload16(qg + (size_t)wi * 8 * 2304, ql + wi * 512);
  }
  // ---- stage rel tables x LOG2E (XOR): rph -> B0, rpw -> B1; row 63 = 0 ----
#pragma unroll
  for (int it = 0; it < 4; ++it) {
    int item = tid + 256 * it;          // 0..1023: 64 rows x 16 ushort4
    int r = item >> 4, c4 = (item & 15) * 4;
    int sw = r * 64 + (((c4 >> 3) ^ (r & 7)) << 3) + (c4 & 7);
    if (r < 63) {
      float4 vh = *(const float4*)(rph + r * 64 + c4);
      vh.x *= LOG2E; vh.y *= LOG2E; vh.z *= LOG2E; vh.w *= LOG2E;
      *(ushort4*)&B0[sw] = cvt4(vh);
      float4 vw = *(const float4*)(rpw + r * 64 + c4);
      vw.x *= LOG2E; vw.y *= LOG2E; vw.z *= LOG2E; vw.w *= LOG2E;
      *(ushort4*)&B1[sw] = cvt4(vw);
    } else {
      ushort4 z = {0, 0, 0, 0};
      *(ushort4*)&B0[sw] = z;
      *(ushort4*)&B1[sw] = z;
    }
  }
  __syncthreads();   // ① staging done (gload16 drained)

  // ---- hoist all fragments (cap 170 VGPR @ 3 waves/EU: no spill risk) ----
  short8 aq[4];
#pragma unroll
  for (int ks = 0; ks < 4; ++ks)
    aq[ks] = *(const short8*)&R0[(wb + l31) * 64 + ((ks * 2 + lh) ^ xr) * 8];

  const int rA = qt * 4 + wv + 31 - l31;       // rph row for this lane
  short8 ah[4];
#pragma unroll
  for (int ks = 0; ks < 4; ++ks)
    ah[ks] = *(const short8*)&B0[rA * 64 + ((ks * 2 + lh) ^ (rA & 7)) * 8];
  short8 aw[8];
#pragma unroll
  for (int ub = 0; ub < 2; ++ub) {
    const int rB = ub * 32 + l31;
#pragma unroll
    for (int ks = 0; ks < 4; ++ks)
      aw[ub * 4 + ks] =
          *(const short8*)&B1[rB * 64 + ((ks * 2 + lh) ^ (rB & 7)) * 8];
  }
  __syncthreads();   // ② all Q/table reads drained before overlay writes

  ushort* Pb2 = R0 + wv * 1280;        // [32 q][40] (R10-proven layout)
  ushort* rhs = R0 + 5120;             // [32 hk][128 q]

  // ---- rh: 4 MFMAs -> rhs (R0 overlay, column-private) ----
  {
    f32x16 sh;
#pragma unroll
    for (int i = 0; i < 16; ++i) sh[i] = 0.f;
#pragma unroll
    for (int ks = 0; ks < 4; ++ks)
      sh = __builtin_amdgcn_mfma_f32_32x32x16_bf16(ah[ks], aq[ks], sh, 0, 0, 0);
#pragma unroll
    for (int reg = 0; reg < 16; ++reg) {
      int rm = (reg & 3) + 8 * (reg >> 2) + 4 * lh;
      rhs[rm * 128 + wb + l31] = f2b(sh[reg]);
    }
  }
  // ---- rw: 8 MFMAs -> U in B0 -> gather rwv (col-private, in-order) ----
  float rwv[16];
  {
    f32x16 su0, su1;
#pragma unroll
    for (int i = 0; i < 16; ++i) { su0[i] = 0.f; su1[i] = 0.f; }
#pragma unroll
    for (int ks = 0; ks < 4; ++ks) {
      su0 = __builtin_amdgcn_mfma_f32_32x32x16_bf16(aw[ks],     aq[ks], su0, 0, 0, 0);
      su1 = __builtin_amdgcn_mfma_f32_32x32x16_bf16(aw[4 + ks], aq[ks], su1, 0, 0, 0);
    }
#pragma unroll
    for (int reg = 0; reg < 16; ++reg) {
      int rm = (reg & 3) + 8 * (reg >> 2) + 4 * lh;
      B0[rm * 128 + wb + l31]        = f2b(su0[reg]);
      B0[(32 + rm) * 128 + wb + l31] = f2b(su1[reg]);
    }
#pragma unroll
    for (int reg = 0; reg < 16; ++reg) {
      int rm = (reg & 3) + 8 * (reg >> 2) + 4 * lh;
      rwv[reg] = b2f(B0[(31 + l31 - rm) * 128 + wb + l31]);  // wq=l31, wk=rm
    }
  }
  __syncthreads();   // ③ U gathers done before tile-0 staging into B0

  // K/V staging ptrs (K at Bt[0,4096), V^T at Bt[4096,8192))
  const ushort* kg = kb + (size_t)(wv * 16 + dr) * 2304 + ccol;
  const ushort* vg = vtg + (size_t)(wv * 16 + dr) * NQ + ccol;
  const int so = wv * 1024;

  // stage tile 0 -> B0
  gload16(kg,            B0 + so);
  gload16(kg + 8 * 2304, B0 + so + 512);
  gload16(vg,            B0 + 4096 + so);
  gload16(vg + 8 * NQ,   B0 + 4096 + so + 512);

  f32x16 oacc0, oacc1;
#pragma unroll
  for (int i = 0; i < 16; ++i) { oacc0[i] = 0.f; oacc1[i] = 0.f; }
  float lacc = 0.f;

  for (int t = 0; t < 16; ++t) {
    __syncthreads();   // drains tile-t loads; prev compute reads of Bn done
    ushort* Bt = (t & 1) ? B1 : B0;
    if (t < 15) {
      ushort* Bn = (t & 1) ? B0 : B1;
      const size_t kn = (size_t)(t + 1) * 64;
      gload16(kg + kn * 2304,            Bn + so);
      gload16(kg + kn * 2304 + 8 * 2304, Bn + so + 512);
      gload16(vg + kn,                   Bn + 4096 + so);
      gload16(vg + kn + 8 * NQ,          Bn + 4096 + so + 512);
    }

    const float rh0 = b2f(rhs[(2 * t) * 128 + wb + l31]);
    const float rh1 = b2f(rhs[(2 * t + 1) * 128 + wb + l31]);

#pragma unroll
    for (int cb = 0; cb < 2; ++cb) {
      f32x16 s;
#pragma unroll
      for (int i = 0; i < 16; ++i) s[i] = 0.f;
#pragma unroll
      for (int ks = 0; ks < 4; ++ks) {
        const int ck = ((ks * 2 + lh) ^ xr) * 8;
        short8 ak = *(const short8*)&Bt[(cb * 32 + l31) * 64 + ck];
        s = __builtin_amdgcn_mfma_f32_32x32x16_bf16(ak, aq[ks], s, 0, 0, 0);
      }
      const float rhv = cb ? rh1 : rh0;
#pragma unroll
      for (int g = 0; g < 4; ++g) {
        float p0 = EXP2(fmaf(s[4 * g + 0], 0.18033688f, rwv[4 * g + 0] + rhv));
        float p1 = EXP2(fmaf(s[4 * g + 1], 0.18033688f, rwv[4 * g + 1] + rhv));
        float p2 = EXP2(fmaf(s[4 * g + 2], 0.18033688f, rwv[4 * g + 2] + rhv));
        float p3 = EXP2(fmaf(s[4 * g + 3], 0.18033688f, rwv[4 * g + 3] + rhv));
        lacc += (p0 + p1) + (p2 + p3);
        uint2 pk; pk.x = pkr(p0, p1); pk.y = pkr(p2, p3);
        *(uint2*)&Pb2[l31 * 40 + 8 * g + 4 * lh] = pk;
      }
#pragma unroll
      for (int ks = 0; ks < 2; ++ks) {
        const int cv = ((cb * 4 + ks * 2 + lh) ^ xr) * 8;
        short8 ap  = *(const short8*)&Pb2[l31 * 40 + ks * 16 + lh * 8];
        short8 bv0 = *(const short8*)&Bt[4096 + l31 * 64 + cv];
        short8 bv1 = *(const short8*)&Bt[4096 + (32 + l31) * 64 + cv];
        oacc0 = __builtin_amdgcn_mfma_f32_32x32x16_bf16(ap, bv0, oacc0, 0, 0, 0);
        oacc1 = __builtin_amdgcn_mfma_f32_32x32x16_bf16(ap, bv1, oacc1, 0, 0, 0);
      }
    }
  }

  lacc += __shfl_xor(lacc, 32);
  const float linv = 1.0f / lacc;
  ushort* ob = O + ((size_t)b * NQ + n0 + wb) * DIM + h * 64;
#pragma unroll
  for (int reg = 0; reg < 16; ++reg) {
    int row = (reg & 3) + 8 * (reg >> 2) + 4 * lh;
    float lq = __shfl(linv, row);
    ob[(size_t)row * DIM + l31]      = f2b(oacc0[reg] * lq);
    ob[(size_t)row * DIM + 32 + l31] = f2b(oacc1[reg] * lq);
  }
}

// ---------------------------------------------------------------------------
extern "C" void kernel_launch(void* const* d_in, const int* in_sizes, int n_in,
                              void* d_out, int out_size, void* d_ws, size_t ws_size,
                              hipStream_t stream) {
  const float* x      = (const float*)d_in[0];
  const float* qkv_w  = (const float*)d_in[1];
  const float* qkv_b  = (const float*)d_in[2];
  const float* proj_w = (const float*)d_in[3];
  const float* proj_b = (const float*)d_in[4];
  const float* rel_h  = (const float*)d_in[5];
  const float* rel_w  = (const float*)d_in[6];
  float* out = (float*)d_out;

  ushort* qkvb = (ushort*)d_ws;                       // 8192 x 2304 bf16 (V region unused)
  ushort* obuf = qkvb + (size_t)8192 * 2304;          // 8192 x 768 bf16
  ushort* Xb   = obuf + (size_t)8192 * DIM;           // 8192 x 768 bf16
  ushort* Wqt  = Xb + (size_t)8192 * DIM;             // 2304 x 768 bf16
  ushort* Wpt  = Wqt + (size_t)2304 * DIM;            // 768 x 768 bf16
  ushort* VTg  = Wpt + (size_t)DIM * DIM;             // 96 x 64 x 1024 bf16

  prep<<<dim3(1344), 256, 0, stream>>>(x, qkv_w, proj_w, Xb, Wqt, Wpt);

  gemm_qkv<<<dim3(1152), 256, 0, stream>>>(Xb, Wqt, qkv_b, qkvb, VTg);

  attn_mfma<<<dim3(96 * 8), 256, 0, stream>>>(qkvb, VTg, rel_h, rel_w, obuf);

  gemm_proj<<<dim3(768), 256, 0, stream>>>(obuf, Wpt, proj_b, out);
}

// Round 14
// 192.000 us; speedup vs baseline: 1.2464x; 1.0095x over previous
//
#include <hip/hip_runtime.h>
#include <hip/hip_bf16.h>
#include <math.h>

// B=8, H=W=32, dim=768, heads=12, hd=64, N=1024, B*heads=96, M=8192
#define DIM   768
#define NHEAD 12
#define NQ    1024

typedef short  short8  __attribute__((ext_vector_type(8)));
typedef unsigned short us8 __attribute__((ext_vector_type(8)));
typedef float  f32x16  __attribute__((ext_vector_type(16)));

#if __has_builtin(__builtin_amdgcn_exp2f)
#define EXP2(x) __builtin_amdgcn_exp2f(x)
#else
#define EXP2(x) __expf(0.69314718056f * (x))
#endif
#define LOG2E 1.44269504089f
#define SCL   0.18033688f          // 0.125 * log2(e)
#define INVSCL 5.54517744448f      // 1 / SCL

__device__ inline ushort f2b(float f) {
  union { float f; unsigned u; } c; c.f = f;
  unsigned r = (c.u + 0x7FFFu + ((c.u >> 16) & 1u)) >> 16;
  return (ushort)r;
}
__device__ inline float b2f(ushort h) {
  union { unsigned u; float f; } c; c.u = ((unsigned)h) << 16;
  return c.f;
}
__device__ inline ushort4 cvt4(float4 v) {
  ushort4 o; o.x = f2b(v.x); o.y = f2b(v.y); o.z = f2b(v.z); o.w = f2b(v.w);
  return o;
}
// pack two f32 -> bf16x2 (round-half-up; 1 v_perm after 2 adds)
__device__ inline unsigned pkr(float a, float b) {
  union { float f; unsigned u; } ca, cb; ca.f = a; cb.f = b;
  return __builtin_amdgcn_perm(cb.u + 0x8000u, ca.u + 0x8000u, 0x07060302u);
}
// async global->LDS, 16 B per lane; LDS dest = wave-uniform base + lane*16
__device__ __forceinline__ void gload16(const void* g, void* l) {
  __builtin_amdgcn_global_load_lds(
      (const __attribute__((address_space(1))) void*)g,
      (__attribute__((address_space(3))) void*)l, 16, 0, 0);
}

// ---------------------------------------------------------------------------
// prep: x -> bf16 Xb;  qkv_w -> Wqt (2304x768 bf16, T);  proj_w -> Wpt (T)
// ---------------------------------------------------------------------------
__global__ __launch_bounds__(256) void prep(
    const float* __restrict__ x, const float* __restrict__ qkv_w,
    const float* __restrict__ proj_w, ushort* __restrict__ Xb,
    ushort* __restrict__ Wqt, ushort* __restrict__ Wpt) {
  __shared__ ushort Ts[64][68];
  const int blk = blockIdx.x, tid = threadIdx.x;
  if (blk < 768) {
    const float4* src = (const float4*)x;
    ushort4* dst = (ushort4*)Xb;
    int base = blk * 2048;
#pragma unroll
    for (int it = 0; it < 8; ++it) {
      int i = base + it * 256 + tid;
      dst[i] = cvt4(src[i]);
    }
    return;
  }
  const float* W; ushort* Wt; int ncols, tk, tn;
  if (blk < 1200) { int t = blk - 768;  W = qkv_w; Wt = Wqt; ncols = 2304; tk = t % 12; tn = t / 12; }
  else            { int t = blk - 1200; W = proj_w; Wt = Wpt; ncols = 768; tk = t % 12; tn = t / 12; }
  const int kb = tk * 64, nb = tn * 64;
#pragma unroll
  for (int rr = 0; rr < 4; ++rr) {
    int r = (tid >> 4) + rr * 16, c4 = (tid & 15) * 4;
    float4 w = *(const float4*)(W + (size_t)(kb + r) * ncols + nb + c4);
    *(ushort4*)&Ts[r][c4] = cvt4(w);
  }
  __syncthreads();
#pragma unroll
  for (int wwi = 0; wwi < 2; ++wwi) {
    int n = (tid >> 3) + wwi * 32, k8 = (tid & 7) * 8;
    us8 v;
#pragma unroll
    for (int j = 0; j < 8; ++j) v[j] = Ts[k8 + j][n];
    *(us8*)(Wt + (size_t)(nb + n) * 768 + kb + k8) = v;
  }
}

// ---------------------------------------------------------------------------
// QKV bf16 MFMA GEMM (128x128, BK=64), gload16 + XOR swizzle, XCD-swizzled.
// V-region cols written transposed to VTg.
// ---------------------------------------------------------------------------
__global__ __launch_bounds__(256, 4) void gemm_qkv(
    const ushort* __restrict__ A, const ushort* __restrict__ BT,
    const float* __restrict__ bias, ushort* __restrict__ Cp,
    ushort* __restrict__ VTg) {
  __shared__ __align__(16) ushort As[128 * 64];
  __shared__ __align__(16) ushort Bs[128 * 64];
  const int tid = threadIdx.x;
  const int flat = blockIdx.x;
  const int g = flat >> 3;
  const int by = (flat & 7) * 8 + g / 18;
  const int bx = g % 18;
  const int bm = by * 128, bn = bx * 128;
  const int lane = tid & 63, wv = tid >> 6;
  const int l31 = lane & 31, lh = lane >> 5;
  const int wm = (wv >> 1) * 64, wn = (wv & 1) * 64;
  const int xr = l31 & 7;

  const int dr = lane >> 3;
  const int ccol = ((lane & 7) ^ dr) * 8;
  const ushort* ag = A + (size_t)(bm + wv * 32 + dr) * 768 + ccol;
  const ushort* bg = BT + (size_t)(bn + wv * 32 + dr) * 768 + ccol;
  ushort* al = &As[wv * 32 * 64];
  ushort* bl = &Bs[wv * 32 * 64];

  f32x16 acc[2][2];
#pragma unroll
  for (int i = 0; i < 2; ++i)
#pragma unroll
    for (int j = 0; j < 2; ++j)
#pragma unroll
      for (int r = 0; r < 16; ++r) acc[i][j][r] = 0.f;

  for (int kt = 0; kt < 768; kt += 64) {
    __syncthreads();
#pragma unroll
    for (int wi = 0; wi < 4; ++wi) {
      gload16(ag + kt + wi * (8 * 768), al + wi * 512);
      gload16(bg + kt + wi * (8 * 768), bl + wi * 512);
    }
    __syncthreads();
#pragma unroll
    for (int ks = 0; ks < 4; ++ks) {
      const int ca = ((ks * 2 + lh) ^ xr) * 8;
      short8 a0 = *(const short8*)&As[(wm + l31) * 64 + ca];
      short8 a1 = *(const short8*)&As[(wm + 32 + l31) * 64 + ca];
      short8 b0 = *(const short8*)&Bs[(wn + l31) * 64 + ca];
      short8 b1 = *(const short8*)&Bs[(wn + 32 + l31) * 64 + ca];
      acc[0][0] = __builtin_amdgcn_mfma_f32_32x32x16_bf16(a0, b0, acc[0][0], 0, 0, 0);
      acc[0][1] = __builtin_amdgcn_mfma_f32_32x32x16_bf16(a0, b1, acc[0][1], 0, 0, 0);
      acc[1][0] = __builtin_amdgcn_mfma_f32_32x32x16_bf16(a1, b0, acc[1][0], 0, 0, 0);
      acc[1][1] = __builtin_amdgcn_mfma_f32_32x32x16_bf16(a1, b1, acc[1][1], 0, 0, 0);
    }
  }

  if (bn < 1536) {
#pragma unroll
    for (int mb = 0; mb < 2; ++mb)
#pragma unroll
      for (int nb = 0; nb < 2; ++nb) {
        int col = bn + wn + nb * 32 + l31;
        float bv = bias[col];
#pragma unroll
        for (int reg = 0; reg < 16; ++reg) {
          int row = bm + wm + mb * 32 + (reg & 3) + 8 * (reg >> 2) + 4 * lh;
          Cp[(size_t)row * 2304 + col] = f2b(acc[mb][nb][reg] + bv);
        }
      }
  } else {
    const int b_ = bm >> 10;
    const int nbase = (bm & 1023) + wm;
#pragma unroll
    for (int nb = 0; nb < 2; ++nb) {
      int col = bn + wn + nb * 32 + l31;          // 1536..2303
      float bv = bias[col];
      int hd_ = col - 1536;
      int h_ = hd_ >> 6, d_ = hd_ & 63;
      ushort* vrow = VTg + ((size_t)(b_ * NHEAD + h_) * 64 + d_) * NQ;
#pragma unroll
      for (int mb = 0; mb < 2; ++mb)
#pragma unroll
        for (int g2 = 0; g2 < 4; ++g2) {
          int n = nbase + mb * 32 + 8 * g2 + 4 * lh;
          ushort4 st;
          st.x = f2b(acc[mb][nb][4 * g2 + 0] + bv);
          st.y = f2b(acc[mb][nb][4 * g2 + 1] + bv);
          st.z = f2b(acc[mb][nb][4 * g2 + 2] + bv);
          st.w = f2b(acc[mb][nb][4 * g2 + 3] + bv);
          *(ushort4*)(vrow + n) = st;
        }
    }
  }
}

// ---------------------------------------------------------------------------
// Proj GEMM: fp32 out = A(8192x768 bf16) @ Wpt^T + bias. 128m x 64n tiles.
// ---------------------------------------------------------------------------
__global__ __launch_bounds__(256, 4) void gemm_proj(
    const ushort* __restrict__ A, const ushort* __restrict__ BT,
    const float* __restrict__ bias, float* __restrict__ C) {
  __shared__ __align__(16) ushort As[128 * 64];
  __shared__ __align__(16) ushort Bs[64 * 64];
  const int tid = threadIdx.x;
  const int flat = blockIdx.x;
  const int g = flat >> 3;
  const int by = (flat & 7) * 8 + g / 12;
  const int bx = g % 12;
  const int bm = by * 128, bn = bx * 64;
  const int lane = tid & 63, wv = tid >> 6;
  const int l31 = lane & 31, lh = lane >> 5;
  const int wm = (wv >> 1) * 64, wn = (wv & 1) * 32;
  const int xr = l31 & 7;

  const int dr = lane >> 3;
  const int ccol = ((lane & 7) ^ dr) * 8;
  const ushort* ag = A + (size_t)(bm + wv * 32 + dr) * 768 + ccol;
  const ushort* bg = BT + (size_t)(bn + wv * 16 + dr) * 768 + ccol;
  ushort* al = &As[wv * 32 * 64];
  ushort* bl = &Bs[wv * 16 * 64];

  f32x16 acc0, acc1;
#pragma unroll
  for (int r = 0; r < 16; ++r) { acc0[r] = 0.f; acc1[r] = 0.f; }

  for (int kt = 0; kt < 768; kt += 64) {
    __syncthreads();
#pragma unroll
    for (int wi = 0; wi < 4; ++wi)
      gload16(ag + kt + wi * (8 * 768), al + wi * 512);
    gload16(bg + kt,            bl);
    gload16(bg + kt + 8 * 768,  bl + 512);
    __syncthreads();
#pragma unroll
    for (int ks = 0; ks < 4; ++ks) {
      const int ca = ((ks * 2 + lh) ^ xr) * 8;
      short8 a0 = *(const short8*)&As[(wm + l31) * 64 + ca];
      short8 a1 = *(const short8*)&As[(wm + 32 + l31) * 64 + ca];
      short8 b0 = *(const short8*)&Bs[(wn + l31) * 64 + ca];
      acc0 = __builtin_amdgcn_mfma_f32_32x32x16_bf16(a0, b0, acc0, 0, 0, 0);
      acc1 = __builtin_amdgcn_mfma_f32_32x32x16_bf16(a1, b0, acc1, 0, 0, 0);
    }
  }

  const int col = bn + wn + l31;
  const float bv = bias[col];
#pragma unroll
  for (int reg = 0; reg < 16; ++reg) {
    int row = bm + wm + (reg & 3) + 8 * (reg >> 2) + 4 * lh;
    C[(size_t)row * 768 + col]        = acc0[reg] + bv;
    C[(size_t)(row + 32) * 768 + col] = acc1[reg] + bv;
  }
}

// ---------------------------------------------------------------------------
// MFMA flash attention, S^T formulation, fused rel-pos bias, double-buffered
// K/V (R13).  R14: (a) row-sum l via MFMA P·1 — reuses PV's A-fragments,
// C-layout pairs reg-for-reg with oacc => shuffle-free epilogue, kills 24
// VALU adds/tile; (b) bias-seeded S-init: S starts at (rw+rh)/SCL so the
// per-element path is mul+exp2 (was add+fma+exp2).
// ---------------------------------------------------------------------------
__global__ __launch_bounds__(256, 3) void attn_mfma(
    const ushort* __restrict__ QKV, const ushort* __restrict__ VTg,
    const float* __restrict__ rph, const float* __restrict__ rpw,
    ushort* __restrict__ O) {
  __shared__ __align__(16) ushort R0[9216];
  __shared__ __align__(16) ushort B0[8192];
  __shared__ __align__(16) ushort B1[8192];

  const int tid = threadIdx.x;
  const int bh = blockIdx.x % 96;
  const int qt = blockIdx.x / 96;
  const int b = bh / NHEAD, h = bh % NHEAD;
  const int n0 = qt * 128;
  const int lane = tid & 63, wv = tid >> 6;
  const int l31 = lane & 31, lh = lane >> 5;
  const int wb = wv * 32;
  const int xr = l31 & 7;

  const ushort* qb = QKV + (size_t)b * NQ * 2304 + h * 64;
  const ushort* kb = qb + DIM;
  const ushort* vtg = VTg + (size_t)bh * 64 * NQ;

  const int dr = lane >> 3;
  const int ccol = ((lane & 7) ^ dr) * 8;

  // ---- stage Q (128x64) via gload16, XOR-swizzled lane-linear ----
  {
    const ushort* qg = qb + (size_t)(n0 + wv * 32 + dr) * 2304 + ccol;
    ushort* ql = R0 + wv * 32 * 64;
#pragma unroll
    for (int wi = 0; wi < 4; ++wi)
      gload16(qg + (size_t)wi * 8 * 2304, ql + wi * 512);
  }
  // ---- stage rel tables x LOG2E (XOR): rph -> B0, rpw -> B1; row 63 = 0 ----
#pragma unroll
  for (int it = 0; it < 4; ++it) {
    int item = tid + 256 * it;          // 0..1023: 64 rows x 16 ushort4
    int r = item >> 4, c4 = (item & 15) * 4;
    int sw = r * 64 + (((c4 >> 3) ^ (r & 7)) << 3) + (c4 & 7);
    if (r < 63) {
      float4 vh = *(const float4*)(rph + r * 64 + c4);
      vh.x *= LOG2E; vh.y *= LOG2E; vh.z *= LOG2E; vh.w *= LOG2E;
      *(ushort4*)&B0[sw] = cvt4(vh);
      float4 vw = *(const float4*)(rpw + r * 64 + c4);
      vw.x *= LOG2E; vw.y *= LOG2E; vw.z *= LOG2E; vw.w *= LOG2E;
      *(ushort4*)&B1[sw] = cvt4(vw);
    } else {
      ushort4 z = {0, 0, 0, 0};
      *(ushort4*)&B0[sw] = z;
      *(ushort4*)&B1[sw] = z;
    }
  }
  __syncthreads();   // ① staging done (gload16 drained)

  // ---- hoist all fragments ----
  short8 aq[4];
#pragma unroll
  for (int ks = 0; ks < 4; ++ks)
    aq[ks] = *(const short8*)&R0[(wb + l31) * 64 + ((ks * 2 + lh) ^ xr) * 8];

  const int rA = qt * 4 + wv + 31 - l31;       // rph row for this lane
  short8 ah[4];
#pragma unroll
  for (int ks = 0; ks < 4; ++ks)
    ah[ks] = *(const short8*)&B0[rA * 64 + ((ks * 2 + lh) ^ (rA & 7)) * 8];
  short8 aw[8];
#pragma unroll
  for (int ub = 0; ub < 2; ++ub) {
    const int rB = ub * 32 + l31;
#pragma unroll
    for (int ks = 0; ks < 4; ++ks)
      aw[ub * 4 + ks] =
          *(const short8*)&B1[rB * 64 + ((ks * 2 + lh) ^ (rB & 7)) * 8];
  }
  __syncthreads();   // ② all Q/table reads drained before overlay writes

  ushort* Pb2 = R0 + wv * 1280;        // [32 q][40] (R10-proven layout)
  ushort* rhs = R0 + 5120;             // [32 hk][128 q]

  // ---- rh: 4 MFMAs -> rhs (R0 overlay, column-private) ----
  {
    f32x16 sh;
#pragma unroll
    for (int i = 0; i < 16; ++i) sh[i] = 0.f;
#pragma unroll
    for (int ks = 0; ks < 4; ++ks)
      sh = __builtin_amdgcn_mfma_f32_32x32x16_bf16(ah[ks], aq[ks], sh, 0, 0, 0);
#pragma unroll
    for (int reg = 0; reg < 16; ++reg) {
      int rm = (reg & 3) + 8 * (reg >> 2) + 4 * lh;
      rhs[rm * 128 + wb + l31] = f2b(sh[reg]);
    }
  }
  // ---- rw: 8 MFMAs -> U in B0 -> gather rwv (col-private, in-order) ----
  float rwvs[16];
  {
    f32x16 su0, su1;
#pragma unroll
    for (int i = 0; i < 16; ++i) { su0[i] = 0.f; su1[i] = 0.f; }
#pragma unroll
    for (int ks = 0; ks < 4; ++ks) {
      su0 = __builtin_amdgcn_mfma_f32_32x32x16_bf16(aw[ks],     aq[ks], su0, 0, 0, 0);
      su1 = __builtin_amdgcn_mfma_f32_32x32x16_bf16(aw[4 + ks], aq[ks], su1, 0, 0, 0);
    }
#pragma unroll
    for (int reg = 0; reg < 16; ++reg) {
      int rm = (reg & 3) + 8 * (reg >> 2) + 4 * lh;
      B0[rm * 128 + wb + l31]        = f2b(su0[reg]);
      B0[(32 + rm) * 128 + wb + l31] = f2b(su1[reg]);
    }
    // gather, pre-scaled by 1/SCL for bias-seeded S-init
#pragma unroll
    for (int reg = 0; reg < 16; ++reg) {
      int rm = (reg & 3) + 8 * (reg >> 2) + 4 * lh;
      rwvs[reg] = b2f(B0[(31 + l31 - rm) * 128 + wb + l31]) * INVSCL;
    }
  }
  __syncthreads();   // ③ U gathers done before tile-0 staging into B0

  // K/V staging ptrs (K at Bt[0,4096), V^T at Bt[4096,8192))
  const ushort* kg = kb + (size_t)(wv * 16 + dr) * 2304 + ccol;
  const ushort* vg = vtg + (size_t)(wv * 16 + dr) * NQ + ccol;
  const int so = wv * 1024;

  // stage tile 0 -> B0
  gload16(kg,            B0 + so);
  gload16(kg + 8 * 2304, B0 + so + 512);
  gload16(vg,            B0 + 4096 + so);
  gload16(vg + 8 * NQ,   B0 + 4096 + so + 512);

  // ones fragment (bf16 1.0 in every element) for the l-row-sum MFMA
  short8 ones;
#pragma unroll
  for (int i = 0; i < 8; ++i) ones[i] = (short)0x3F80;

  f32x16 oacc0, oacc1, lacc16;
#pragma unroll
  for (int i = 0; i < 16; ++i) { oacc0[i] = 0.f; oacc1[i] = 0.f; lacc16[i] = 0.f; }

  for (int t = 0; t < 16; ++t) {
    __syncthreads();   // drains tile-t loads; prev compute reads of Bn done
    ushort* Bt = (t & 1) ? B1 : B0;
    if (t < 15) {
      ushort* Bn = (t & 1) ? B0 : B1;
      const size_t kn = (size_t)(t + 1) * 64;
      gload16(kg + kn * 2304,            Bn + so);
      gload16(kg + kn * 2304 + 8 * 2304, Bn + so + 512);
      gload16(vg + kn,                   Bn + 4096 + so);
      gload16(vg + kn + 8 * NQ,          Bn + 4096 + so + 512);
    }

    const float rh0s = b2f(rhs[(2 * t) * 128 + wb + l31]) * INVSCL;
    const float rh1s = b2f(rhs[(2 * t + 1) * 128 + wb + l31]) * INVSCL;

#pragma unroll
    for (int cb = 0; cb < 2; ++cb) {
      const float rhvs = cb ? rh1s : rh0s;
      // bias-seeded S init: after MFMA, s = QK + (rw+rh)/SCL
      f32x16 s;
#pragma unroll
      for (int i = 0; i < 16; ++i) s[i] = rwvs[i] + rhvs;
#pragma unroll
      for (int ks = 0; ks < 4; ++ks) {
        const int ck = ((ks * 2 + lh) ^ xr) * 8;
        short8 ak = *(const short8*)&Bt[(cb * 32 + l31) * 64 + ck];
        s = __builtin_amdgcn_mfma_f32_32x32x16_bf16(ak, aq[ks], s, 0, 0, 0);
      }
#pragma unroll
      for (int g = 0; g < 4; ++g) {
        float p0 = EXP2(s[4 * g + 0] * SCL);
        float p1 = EXP2(s[4 * g + 1] * SCL);
        float p2 = EXP2(s[4 * g + 2] * SCL);
        float p3 = EXP2(s[4 * g + 3] * SCL);
        uint2 pk; pk.x = pkr(p0, p1); pk.y = pkr(p2, p3);
        *(uint2*)&Pb2[l31 * 40 + 8 * g + 4 * lh] = pk;
      }
#pragma unroll
      for (int ks = 0; ks < 2; ++ks) {
        const int cv = ((cb * 4 + ks * 2 + lh) ^ xr) * 8;
        short8 ap  = *(const short8*)&Pb2[l31 * 40 + ks * 16 + lh * 8];
        short8 bv0 = *(const short8*)&Bt[4096 + l31 * 64 + cv];
        short8 bv1 = *(const short8*)&Bt[4096 + (32 + l31) * 64 + cv];
        oacc0  = __builtin_amdgcn_mfma_f32_32x32x16_bf16(ap, bv0, oacc0, 0, 0, 0);
        oacc1  = __builtin_amdgcn_mfma_f32_32x32x16_bf16(ap, bv1, oacc1, 0, 0, 0);
        lacc16 = __builtin_amdgcn_mfma_f32_32x32x16_bf16(ap, ones, lacc16, 0, 0, 0);
      }
    }
  }

  // epilogue: lacc16[reg] = l for q-row rm (same reg-map as oacc) — no shuffles
  ushort* ob = O + ((size_t)b * NQ + n0 + wb) * DIM + h * 64;
#pragma unroll
  for (int reg = 0; reg < 16; ++reg) {
    int row = (reg & 3) + 8 * (reg >> 2) + 4 * lh;
    float lq = 1.0f / lacc16[reg];
    ob[(size_t)row * DIM + l31]      = f2b(oacc0[reg] * lq);
    ob[(size_t)row * DIM + 32 + l31] = f2b(oacc1[reg] * lq);
  }
}

// ---------------------------------------------------------------------------
extern "C" void kernel_launch(void* const* d_in, const int* in_sizes, int n_in,
                              void* d_out, int out_size, void* d_ws, size_t ws_size,
                              hipStream_t stream) {
  const float* x      = (const float*)d_in[0];
  const float* qkv_w  = (const float*)d_in[1];
  const float* qkv_b  = (const float*)d_in[2];
  const float* proj_w = (const float*)d_in[3];
  const float* proj_b = (const float*)d_in[4];
  const float* rel_h  = (const float*)d_in[5];
  const float* rel_w  = (const float*)d_in[6];
  float* out = (float*)d_out;

  ushort* qkvb = (ushort*)d_ws;                       // 8192 x 2304 bf16 (V region unused)
  ushort* obuf = qkvb + (size_t)8192 * 2304;          // 8192 x 768 bf16
  ushort* Xb   = obuf + (size_t)8192 * DIM;           // 8192 x 768 bf16
  ushort* Wqt  = Xb + (size_t)8192 * DIM;             // 2304 x 768 bf16
  ushort* Wpt  = Wqt + (size_t)2304 * DIM;            // 768 x 768 bf16
  ushort* VTg  = Wpt + (size_t)DIM * DIM;             // 96 x 64 x 1024 bf16

  prep<<<dim3(1344), 256, 0, stream>>>(x, qkv_w, proj_w, Xb, Wqt, Wpt);

  gemm_qkv<<<dim3(1152), 256, 0, stream>>>(Xb, Wqt, qkv_b, qkvb, VTg);

  attn_mfma<<<dim3(96 * 8), 256, 0, stream>>>(qkvb, VTg, rel_h, rel_w, obuf);

  gemm_proj<<<dim3(768), 256, 0, stream>>>(obuf, Wpt, proj_b, out);
}